// Round 14
// baseline (117.186 us; speedup 1.0000x reference)
//
#include <hip/hip_runtime.h>
#include <math.h>

#define Bsz 4
#define T 2048
#define D 128
#define H 8
#define HS 16
#define E 8
#define FF 512
#define N (Bsz*T)     // 8192
#define NQ (Bsz*H*T)  // 65536 query rows
#define EPS 1e-5f
#define SCALE2 0.36067376f   // 0.25 * log2(e)
#define SPLITS 4             // 512 keys per split

typedef _Float16 h4 __attribute__((ext_vector_type(4)));
typedef _Float16 h2 __attribute__((ext_vector_type(2)));
typedef float f4 __attribute__((ext_vector_type(4)));
#define MFMA16 __builtin_amdgcn_mfma_f32_16x16x16f16
#define EXP2(x) __builtin_amdgcn_exp2f(x)

// ---------------- merged MoE weight packing: z = e*2 + (0:w1, 1:w2) ----------------
__global__ void pack_moe(const float* __restrict__ w1, const float* __restrict__ w2,
                         _Float16* __restrict__ w1pk, _Float16* __restrict__ w2pk) {
  int ft = blockIdx.x, kd = blockIdx.y;
  int e = blockIdx.z >> 1, m = blockIdx.z & 1;
  int l = threadIdx.x, lg = l >> 4, lr = l & 15;
  h4 v;
  if (m == 0) {
    const float* src = w1 + (size_t)e * D * FF;
#pragma unroll
    for (int i = 0; i < 4; ++i)
      v[i] = (_Float16)src[(size_t)(16 * kd + 4 * lg + i) * FF + 16 * ft + lr];
    ((h4*)w1pk)[(((size_t)e * 32 + ft) * 8 + kd) * 64 + l] = v;
  } else {
    const float* src = w2 + (size_t)e * FF * D;
#pragma unroll
    for (int i = 0; i < 4; ++i)
      v[i] = (_Float16)src[(size_t)(16 * ft + 4 * lg + i) * D + 16 * kd + lr];
    ((h4*)w2pk)[(((size_t)e * 32 + ft) * 8 + kd) * 64 + l] = v;
  }
}

// ---------------- merged attn-side packing: z = 0..2 qkv (hi/lo), z=3 wp (hi/lo) --------
__global__ void pack_attn(const float* __restrict__ wq, const float* __restrict__ wk,
                          const float* __restrict__ wv, const float* __restrict__ wp,
                          _Float16* __restrict__ wqh, _Float16* __restrict__ wql,
                          _Float16* __restrict__ wph, _Float16* __restrict__ wpl) {
  int ot = blockIdx.x, kd = blockIdx.y, m = blockIdx.z;
  int l = threadIdx.x, lg = l >> 4, lr = l & 15;
  h4 vh, vl;
  if (m < 3) {
    const float* W = (m == 0 ? wq : (m == 1 ? wk : wv));
    float sc = (m == 0) ? SCALE2 : 1.f;
#pragma unroll
    for (int i = 0; i < 4; ++i) {
      float w = W[((size_t)ot * D + 16 * kd + 4 * lg + i) * HS + lr] * sc;
      _Float16 h = (_Float16)w;
      vh[i] = h;
      vl[i] = (_Float16)(w - (float)h);
    }
    size_t idx = (((size_t)m * 8 + ot) * 8 + kd) * 64 + l;
    ((h4*)wqh)[idx] = vh;
    ((h4*)wql)[idx] = vl;
  } else {
#pragma unroll
    for (int i = 0; i < 4; ++i) {
      float w = wp[(size_t)(16 * kd + 4 * lg + i) * D + 16 * ot + lr];
      _Float16 h = (_Float16)w;
      vh[i] = h;
      vl[i] = (_Float16)(w - (float)h);
    }
    size_t idx = ((size_t)ot * 8 + kd) * 64 + l;
    ((h4*)wph)[idx] = vh;
    ((h4*)wpl)[idx] = vl;
  }
}

// ---------------- fused LN1 + QKV split MFMA: 16 tokens, 8 waves (wave = head) ----------
__global__ __launch_bounds__(512) void qkv_mfma(
    const float* __restrict__ x, const float* __restrict__ g, const float* __restrict__ bln,
    const _Float16* __restrict__ wh, const _Float16* __restrict__ wl,
    _Float16* __restrict__ qh, _Float16* __restrict__ kh, _Float16* __restrict__ vTh) {
  __shared__ _Float16 xsh[16][136];
  __shared__ _Float16 xsl[16][136];
  int n0 = blockIdx.x * 16;
  int b = n0 >> 11, t0 = n0 & (T - 1);
  int tid = threadIdx.x;
  {  // LN for 16 rows: 32 threads/row, 4 elems/thread
    int i = tid >> 5, c = tid & 31;
    float4 v = *(const float4*)(x + (size_t)(n0 + i) * D + 4 * c);
    float s  = v.x + v.y + v.z + v.w;
    float s2 = v.x*v.x + v.y*v.y + v.z*v.z + v.w*v.w;
#pragma unroll
    for (int off = 16; off >= 1; off >>= 1) { s += __shfl_xor(s, off); s2 += __shfl_xor(s2, off); }
    float m = s * (1.f / D);
    float var = s2 * (1.f / D) - m * m;
    float r = rsqrtf(var + EPS);
    float4 gg = *(const float4*)(g + 4 * c);
    float4 bb = *(const float4*)(bln + 4 * c);
    float o0 = (v.x - m) * r * gg.x + bb.x;
    float o1 = (v.y - m) * r * gg.y + bb.y;
    float o2 = (v.z - m) * r * gg.z + bb.z;
    float o3 = (v.w - m) * r * gg.w + bb.w;
    _Float16 h0 = (_Float16)o0, h1 = (_Float16)o1, h2_ = (_Float16)o2, h3 = (_Float16)o3;
    *(h4*)&xsh[i][4 * c] = (h4){h0, h1, h2_, h3};
    *(h4*)&xsl[i][4 * c] = (h4){(_Float16)(o0 - (float)h0), (_Float16)(o1 - (float)h1),
                                (_Float16)(o2 - (float)h2_), (_Float16)(o3 - (float)h3)};
  }
  __syncthreads();
  int ot = tid >> 6;            // wave id = head 0..7
  int l = tid & 63, lg = l >> 4, lr = l & 15;
  h4 xfh[8], xfl[8];
#pragma unroll
  for (int kd = 0; kd < 8; ++kd) {
    xfh[kd] = *(const h4*)&xsh[lr][16 * kd + 4 * lg];
    xfl[kd] = *(const h4*)&xsl[lr][16 * kd + 4 * lg];
  }
  const h4* wbh = (const h4*)wh + l;
  const h4* wbl = (const h4*)wl + l;
  f4 aq = {0.f,0.f,0.f,0.f}, ak = aq, av = aq;
#pragma unroll
  for (int kd = 0; kd < 8; ++kd) {
    h4 wqh_ = wbh[((0 * 8 + ot) * 8 + kd) * 64];
    h4 wkh_ = wbh[((1 * 8 + ot) * 8 + kd) * 64];
    h4 wvh_ = wbh[((2 * 8 + ot) * 8 + kd) * 64];
    h4 wql_ = wbl[((0 * 8 + ot) * 8 + kd) * 64];
    h4 wkl_ = wbl[((1 * 8 + ot) * 8 + kd) * 64];
    h4 wvl_ = wbl[((2 * 8 + ot) * 8 + kd) * 64];
    aq = MFMA16(wqh_, xfh[kd], aq, 0, 0, 0);
    ak = MFMA16(wkh_, xfh[kd], ak, 0, 0, 0);
    av = MFMA16(xfh[kd], wvh_, av, 0, 0, 0);
    aq = MFMA16(wql_, xfh[kd], aq, 0, 0, 0);
    ak = MFMA16(wkl_, xfh[kd], ak, 0, 0, 0);
    av = MFMA16(xfl[kd], wvh_, av, 0, 0, 0);
    aq = MFMA16(wqh_, xfl[kd], aq, 0, 0, 0);
    ak = MFMA16(wkh_, xfl[kd], ak, 0, 0, 0);
    av = MFMA16(xfh[kd], wvl_, av, 0, 0, 0);
  }
  h4 q4 = {(_Float16)aq.x, (_Float16)aq.y, (_Float16)aq.z, (_Float16)aq.w};
  h4 k4 = {(_Float16)ak.x, (_Float16)ak.y, (_Float16)ak.z, (_Float16)ak.w};
  size_t qoff = ((size_t)(b * H + ot) * T + t0 + lr) * 16 + 4 * lg;
  *(h4*)(qh + qoff) = q4;
  *(h4*)(kh + qoff) = k4;
  h4 v4 = {(_Float16)av.x, (_Float16)av.y, (_Float16)av.z, (_Float16)av.w};
  *(h4*)(vTh + ((size_t)(b * H + ot) * 16 + lr) * T + t0 + 4 * lg) = v4;
}

// ---------------- MFMA flash attention partial: SPLITS=4 (512 keys/split) ----------
// per bh: pairs (qt,s) with 8s<=qt; 80 pairs grouped by c=#splits(qt)=1..4 (8 qt per c)
__global__ __launch_bounds__(256) void attn_mfma(
    const _Float16* __restrict__ q, const _Float16* __restrict__ k,
    const _Float16* __restrict__ vT, float* __restrict__ part) {
  int bh = blockIdx.y;
  int p = blockIdx.x * 4 + (threadIdx.x >> 6);   // active pair index 0..79
  int c = 1;
  while (p >= 4 * c * (c - 1) + 8 * c) ++c;      // c in 1..4 (wave-uniform)
  int rem = p - 4 * c * (c - 1);
  int qt = (c - 1) * 8 + rem / c;
  int s = rem % c;
  int glo = 8 * s;
  int ghi = min(glo + 8, qt + 1);
  int l = threadIdx.x & 63;
  int lg = l >> 4, lr = l & 15;
  int q0 = qt * 64;
  const h4* qp = (const h4*)(q + ((size_t)bh * T + q0 + lr) * 16 + 4 * lg);
  h4 qf[4];
#pragma unroll
  for (int nt = 0; nt < 4; ++nt) qf[nt] = qp[nt * 64];
  f4 o0 = {0.f,0.f,0.f,0.f}, o1 = o0, o2 = o0, o3 = o0;
  float L0 = 0.f, L1 = 0.f, L2 = 0.f, L3 = 0.f;
  h4 kf[4], vf[4], kf2[4], vf2[4];
#define LOADKV(G, KK, VV) do { \
    int k0g = (G) * 64; \
    const h4* kp = (const h4*)(k + ((size_t)bh * T + k0g + lr) * 16 + 4 * lg); \
    _Pragma("unroll") for (int mt = 0; mt < 4; ++mt) KK[mt] = kp[mt * 64]; \
    const h4* vp = (const h4*)(vT + ((size_t)bh * 16 + lr) * T + k0g + 4 * lg); \
    _Pragma("unroll") for (int mt = 0; mt < 4; ++mt) VV[mt] = vp[mt * 4]; \
  } while (0)
  LOADKV(glo, kf, vf);
  for (int g = glo; g < ghi; ++g) {
    bool more = (g + 1 < ghi);
    if (more) LOADKV(g + 1, kf2, vf2);
    f4 z = {0.f,0.f,0.f,0.f};
    f4 sc[4][4];
#pragma unroll
    for (int mt = 0; mt < 4; ++mt)
#pragma unroll
      for (int nt = 0; nt < 4; ++nt)
        sc[mt][nt] = MFMA16(kf[mt], qf[nt], z, 0, 0, 0);
    if (g == qt) {  // diagonal tile: mask key > query
#pragma unroll
      for (int mt = 0; mt < 4; ++mt)
#pragma unroll
        for (int nt = 0; nt < 4; ++nt) {
          int kb = 16 * mt + 4 * lg, qb = 16 * nt + lr;
          if (kb + 0 > qb) sc[mt][nt].x = -1e30f;
          if (kb + 1 > qb) sc[mt][nt].y = -1e30f;
          if (kb + 2 > qb) sc[mt][nt].z = -1e30f;
          if (kb + 3 > qb) sc[mt][nt].w = -1e30f;
        }
    }
#define PROC(NT, L, O) do { \
    h4 pf[4]; \
    _Pragma("unroll") for (int mt = 0; mt < 4; ++mt) { \
      f4 a = sc[mt][NT]; h4 pv; float ex; \
      ex = EXP2(a.x); L += ex; pv.x = (_Float16)ex; \
      ex = EXP2(a.y); L += ex; pv.y = (_Float16)ex; \
      ex = EXP2(a.z); L += ex; pv.z = (_Float16)ex; \
      ex = EXP2(a.w); L += ex; pv.w = (_Float16)ex; \
      pf[mt] = pv; } \
    _Pragma("unroll") for (int mt = 0; mt < 4; ++mt) \
      O = MFMA16(vf[mt], pf[mt], O, 0, 0, 0); \
  } while (0)
    PROC(0, L0, o0);
    PROC(1, L1, o1);
    PROC(2, L2, o2);
    PROC(3, L3, o3);
#undef PROC
    if (more) {
#pragma unroll
      for (int mt = 0; mt < 4; ++mt) { kf[mt] = kf2[mt]; vf[mt] = vf2[mt]; }
    }
  }
#undef LOADKV
  L0 += __shfl_xor(L0, 16); L0 += __shfl_xor(L0, 32);
  L1 += __shfl_xor(L1, 16); L1 += __shfl_xor(L1, 32);
  L2 += __shfl_xor(L2, 16); L2 += __shfl_xor(L2, 32);
  L3 += __shfl_xor(L3, 16); L3 += __shfl_xor(L3, 32);
  float* pb = part + (size_t)s * 18 * NQ;
  int nbase = bh * T + q0 + lr;
#define WR(NT, L, O) do { int n = nbase + 16 * NT; \
    pb[(4 * lg + 0) * NQ + n] = O.x; pb[(4 * lg + 1) * NQ + n] = O.y; \
    pb[(4 * lg + 2) * NQ + n] = O.z; pb[(4 * lg + 3) * NQ + n] = O.w; \
    if (lg == 0) pb[16 * NQ + n] = L; \
  } while (0)
  WR(0, L0, o0);
  WR(1, L1, o1);
  WR(2, L2, o2);
  WR(3, L3, o3);
#undef WR
}

// ------- fused combine + proj + residual + LN2 + GATE: 16 tokens, 512 threads -------
__global__ __launch_bounds__(512) void comb_proj(
    const float* __restrict__ part,
    const _Float16* __restrict__ wpph, const _Float16* __restrict__ wppl,
    const float* __restrict__ bp, const float* __restrict__ x,
    const float* __restrict__ ln2g, const float* __restrict__ ln2b,
    const float* __restrict__ wg,
    float* __restrict__ x1, _Float16* __restrict__ xh,
    int* __restrict__ wcnt, float* __restrict__ wpsum,
    int4* __restrict__ tokinfo, float2* __restrict__ gws) {
  __shared__ float xP[16][132];
  int n0 = blockIdx.x * 16;
  int b = n0 >> 11, t0 = n0 & (T - 1);
  int blk = blockIdx.x;
  int tid = threadIdx.x;
  int ns = (t0 >> 9) + 1;   // splits covering this block (uniform; 512 keys/split)
  {  // phase 1: combine split partials -> xP[token][d]
    int i = tid & 15, h = (tid >> 4) & 7, r = tid >> 7;
    int n = (b * H + h) * T + t0 + i;
    float a0 = 0.f, a1 = 0.f, a2 = 0.f, a3 = 0.f, L = 0.f;
    for (int s = 0; s < ns; ++s) {
      const float* pb = part + (size_t)s * 18 * NQ;
      L  += pb[16 * NQ + n];
      a0 += pb[(4 * r + 0) * NQ + n];
      a1 += pb[(4 * r + 1) * NQ + n];
      a2 += pb[(4 * r + 2) * NQ + n];
      a3 += pb[(4 * r + 3) * NQ + n];
    }
    float inv = 1.f / L;
    float4 o = {a0 * inv, a1 * inv, a2 * inv, a3 * inv};
    *(float4*)&xP[i][h * 16 + 4 * r] = o;
  }
  __syncthreads();
  // phase 2: proj via split MFMA (wave ot = output tile)
  int ot = tid >> 6;
  int l = tid & 63, lg = l >> 4, lr = l & 15;
  h4 afh[8], afl[8];
#pragma unroll
  for (int kd = 0; kd < 8; ++kd) {
    float4 v = *(const float4*)&xP[lr][16 * kd + 4 * lg];
    _Float16 h0 = (_Float16)v.x, h1 = (_Float16)v.y, h2_ = (_Float16)v.z, h3 = (_Float16)v.w;
    afh[kd] = (h4){h0, h1, h2_, h3};
    afl[kd] = (h4){(_Float16)(v.x - (float)h0), (_Float16)(v.y - (float)h1),
                   (_Float16)(v.z - (float)h2_), (_Float16)(v.w - (float)h3)};
  }
  const h4* wbh = (const h4*)wpph + l;
  const h4* wbl = (const h4*)wppl + l;
  f4 acc = {0.f,0.f,0.f,0.f};
#pragma unroll
  for (int kd = 0; kd < 8; ++kd) {
    h4 wh_ = wbh[(ot * 8 + kd) * 64];
    h4 wl_ = wbl[(ot * 8 + kd) * 64];
    acc = MFMA16(wh_, afh[kd], acc, 0, 0, 0);
    acc = MFMA16(wl_, afh[kd], acc, 0, 0, 0);
    acc = MFMA16(wh_, afl[kd], acc, 0, 0, 0);
  }
  int o = 16 * ot + 4 * lg;
  float4 xr = *(const float4*)(x + (size_t)(n0 + lr) * D + o);
  float4 bb = *(const float4*)(bp + o);
  float4 ov = {acc.x + xr.x + bb.x, acc.y + xr.y + bb.y,
               acc.z + xr.z + bb.z, acc.w + xr.w + bb.w};
  *(float4*)(x1 + (size_t)(n0 + lr) * D + o) = ov;
  __syncthreads();            // all xP reads done
  *(float4*)&xP[lr][o] = ov;  // stage x1 rows for LN2
  __syncthreads();
  {  // phase 3: LN2 -> xh (f16, moe) + xP (f32, gate)
    int i = tid >> 5, c = tid & 31;
    float4 v = *(const float4*)&xP[i][4 * c];
    float s  = v.x + v.y + v.z + v.w;
    float s2 = v.x*v.x + v.y*v.y + v.z*v.z + v.w*v.w;
#pragma unroll
    for (int off = 16; off >= 1; off >>= 1) { s += __shfl_xor(s, off); s2 += __shfl_xor(s2, off); }
    float m = s * (1.f / D);
    float var = s2 * (1.f / D) - m * m;
    float r = rsqrtf(var + EPS);
    float4 gg = *(const float4*)(ln2g + 4 * c);
    float4 bv = *(const float4*)(ln2b + 4 * c);
    float4 on = {(v.x - m) * r * gg.x + bv.x, (v.y - m) * r * gg.y + bv.y,
                 (v.z - m) * r * gg.z + bv.z, (v.w - m) * r * gg.w + bv.w};
    h4 oh = {(_Float16)on.x, (_Float16)on.y, (_Float16)on.z, (_Float16)on.w};
    *(h4*)(xh + (size_t)(n0 + i) * D + 4 * c) = oh;
    *(float4*)&xP[i][4 * c] = on;    // own slot; row consumed whole after sync
  }
  __syncthreads();
  if (tid < 16) {  // phase 4: gate — byte-identical serial math per token
    int n = n0 + tid;
    float lgt[E];
#pragma unroll
    for (int e = 0; e < E; ++e) lgt[e] = 0.f;
    for (int dq = 0; dq < 32; ++dq) {
      float4 xv = *(const float4*)&xP[tid][4 * dq];
      int d = dq * 4;
#pragma unroll
      for (int e = 0; e < E; ++e)
        lgt[e] += xv.x * wg[d*E + e] + xv.y * wg[(d+1)*E + e]
                + xv.z * wg[(d+2)*E + e] + xv.w * wg[(d+3)*E + e];
    }
    float mx = lgt[0];
#pragma unroll
    for (int e = 1; e < E; ++e) mx = fmaxf(mx, lgt[e]);
    float p[E]; float s = 0.f;
#pragma unroll
    for (int e = 0; e < E; ++e) { p[e] = __expf(lgt[e] - mx); s += p[e]; }
    float invs = 1.f / s;
#pragma unroll
    for (int e = 0; e < E; ++e) p[e] *= invs;
#pragma unroll
    for (int e = 0; e < E; ++e) {   // 16-lane reduce (lanes 0..15 all active)
      float ve = p[e];
      ve += __shfl_xor(ve, 8); ve += __shfl_xor(ve, 4);
      ve += __shfl_xor(ve, 2); ve += __shfl_xor(ve, 1);
      if (tid == 0) wpsum[blk * E + e] = ve;
    }
    int i1 = 0; float p1 = p[0];
#pragma unroll
    for (int e = 1; e < E; ++e) if (p[e] > p1) { p1 = p[e]; i1 = e; }
    int i2 = (i1 == 0) ? 1 : 0; float p2 = p[i2];
#pragma unroll
    for (int e = 0; e < E; ++e) if (e != i1 && p[e] > p2) { p2 = p[e]; i2 = e; }
    float gden = 1.f / (p1 + p2);
    unsigned long long lt = (1ULL << tid) - 1ULL;
    int woff0 = 0, woff1 = 0;
    int c0[E], ctot[E];
#pragma unroll
    for (int e = 0; e < E; ++e) {
      unsigned long long m0 = __ballot(i1 == e);
      c0[e] = __popcll(m0);
      if (i1 == e) woff0 = __popcll(m0 & lt);
    }
#pragma unroll
    for (int e = 0; e < E; ++e) {
      unsigned long long m1 = __ballot(i2 == e);
      if (i2 == e) woff1 = c0[e] + __popcll(m1 & lt);
      ctot[e] = c0[e] + __popcll(m1);
    }
    if (tid == 0) {
#pragma unroll
      for (int e = 0; e < E; ++e) wcnt[blk * E + e] = ctot[e];
    }
    tokinfo[n] = make_int4(i1, woff0, i2, woff1);
    gws[n] = make_float2(p1 * gden, p2 * gden);
  }
}

// ------- gate scan+scatter: each block scans all 512x8 counts, scatters 64 tokens -------
__global__ __launch_bounds__(64) void gate_scat(
    const int* __restrict__ wcnt, const float* __restrict__ wpsum,
    const int4* __restrict__ tokinfo, const float2* __restrict__ gws,
    int* __restrict__ ltok, int* __restrict__ sidx, float* __restrict__ gwn,
    int* __restrict__ ecnt, float* __restrict__ psum) {
  __shared__ int pre[512 * E];   // 16 KB; becomes exclusive prefix per expert
  __shared__ int segsum[8][E];
  int tid = threadIdx.x, blk = blockIdx.x;
  for (int i = tid; i < 512 * E; i += 64) pre[i] = wcnt[i];
  __syncthreads();
  {  // level 1: segment sums (8 segments x 8 experts, one thread each)
    int e = tid & 7, seg = tid >> 3;
    int s = 0;
    for (int b = seg * 64; b < seg * 64 + 64; ++b) s += pre[b * E + e];
    segsum[seg][e] = s;
  }
  __syncthreads();
  if (tid < 8) {  // level 2: scan segments for expert tid
    int run = 0;
    for (int g = 0; g < 8; ++g) { int c = segsum[g][tid]; segsum[g][tid] = run; run += c; }
    if (blk == 0) ecnt[tid] = run;
  } else if (blk == 0 && tid >= 16 && tid < 24) {
    int e = tid - 16;
    float s = 0.f;
    for (int b = 0; b < 512; ++b) s += wpsum[b * E + e];
    psum[e] = s;
  }
  __syncthreads();
  {  // level 3: in-place exclusive prefix within segment
    int e = tid & 7, seg = tid >> 3;
    int run = segsum[seg][e];
    for (int b = seg * 64; b < seg * 64 + 64; ++b) {
      int c = pre[b * E + e]; pre[b * E + e] = run; run += c;
    }
  }
  __syncthreads();
  int n = blk * 64 + tid;
  int4 ti = tokinfo[n];
  float2 g = gws[n];
  int sb = n >> 4;              // source 16-token block
  int pos0 = pre[sb * E + ti.x] + ti.y;
  int pos1 = pre[sb * E + ti.z] + ti.w;
  ltok[ti.x * N + pos0] = n;
  ltok[ti.z * N + pos1] = n;
  sidx[2 * n]     = ti.x * N + pos0;
  sidx[2 * n + 1] = ti.z * N + pos1;
  gwn[2 * n]     = g.x;
  gwn[2 * n + 1] = g.y;
}

// ---------------- MFMA grouped expert FFN: 16 tokens/block, 4-way FF split ----------------
__global__ __launch_bounds__(256) void moe_mfma(
    const _Float16* __restrict__ xh, const _Float16* __restrict__ w1pk,
    const float* __restrict__ b1, const _Float16* __restrict__ w2pk,
    const float* __restrict__ b2, const int* __restrict__ ecnt,
    const int* __restrict__ ltok, float* __restrict__ eo) {
  int e = blockIdx.y;
  int cnt = ecnt[e];
  int t0 = blockIdx.x * 16;
  if (t0 >= cnt) return;
  __shared__ int toks[16];
  __shared__ f4 red[3][8][64];
  int tid = threadIdx.x;
  if (tid < 16)
    toks[tid] = (t0 + tid < cnt) ? ltok[e * N + t0 + tid] : -1;
  __syncthreads();
  int fh = tid >> 6;            // wave = FF quarter 0..3
  int l = tid & 63;
  int lg = l >> 4, lr = l & 15;
  int tok = toks[lr];
  const h4* xp = (const h4*)(xh + (size_t)(tok < 0 ? 0 : tok) * D + 4 * lg);
  h4 xf[8];
#pragma unroll
  for (int kd = 0; kd < 8; ++kd) xf[kd] = xp[kd * 4];
  f4 oacc[8];
#pragma unroll
  for (int dt = 0; dt < 8; ++dt) oacc[dt] = (f4){0.f,0.f,0.f,0.f};
  const float* b1e = b1 + e * FF;
  const h4* w1b = (const h4*)w1pk + ((size_t)e * 32 + 8 * fh) * 8 * 64 + l;
  const h4* w2b = (const h4*)w2pk + ((size_t)e * 32 + 8 * fh) * 8 * 64 + l;
#pragma unroll 2
  for (int ftl = 0; ftl < 8; ++ftl) {
    f4 ha = {0.f,0.f,0.f,0.f};
#pragma unroll
    for (int kd = 0; kd < 8; ++kd)
      ha = MFMA16(w1b[(ftl * 8 + kd) * 64], xf[kd], ha, 0, 0, 0);
    int ft = 8 * fh + ftl;
    float4 bb = *(const float4*)&b1e[16 * ft + 4 * lg];
    h4 pf;
    {
      float z;
      z = ha.x + bb.x; pf.x = (_Float16)(0.5f * z * (1.f + erff(z * 0.70710678f)));
      z = ha.y + bb.y; pf.y = (_Float16)(0.5f * z * (1.f + erff(z * 0.70710678f)));
      z = ha.z + bb.z; pf.z = (_Float16)(0.5f * z * (1.f + erff(z * 0.70710678f)));
      z = ha.w + bb.w; pf.w = (_Float16)(0.5f * z * (1.f + erff(z * 0.70710678f)));
    }
#pragma unroll
    for (int dt = 0; dt < 8; ++dt)
      oacc[dt] = MFMA16(w2b[(ftl * 8 + dt) * 64], pf, oacc[dt], 0, 0, 0);
  }
  if (fh >= 1) {
#pragma unroll
    for (int dt = 0; dt < 8; ++dt) red[fh - 1][dt][l] = oacc[dt];
  }
  __syncthreads();
  if (fh == 0 && tok >= 0) {
    const float* b2e = b2 + e * D;
    float* eop = eo + ((size_t)(e * N + t0 + lr)) * 128;
#pragma unroll
    for (int dt = 0; dt < 8; ++dt) {
      f4 r0 = red[0][dt][l], r1 = red[1][dt][l], r2 = red[2][dt][l];
      float4 bb = *(const float4*)&b2e[16 * dt + 4 * lg];
      float4 o4 = {oacc[dt].x + r0.x + r1.x + r2.x + bb.x,
                   oacc[dt].y + r0.y + r1.y + r2.y + bb.y,
                   oacc[dt].z + r0.z + r1.z + r2.z + bb.z,
                   oacc[dt].w + r0.w + r1.w + r2.w + bb.w};
      *(float4*)(eop + 16 * dt + 4 * lg) = o4;
    }
  }
}

// ---------------- finalize: out = x1 + g0*eo[i0] + g1*eo[i1]; aux ----------------
__global__ void finalize_kernel(const float* __restrict__ x1, const float* __restrict__ eo,
                                const int* __restrict__ sidx, const float* __restrict__ gwn,
                                const float* __restrict__ psum, const int* __restrict__ ecnt,
                                float* __restrict__ out) {
  int idx = blockIdx.x * 256 + threadIdx.x;   // float4 index, N*D/4 total
  int n = idx >> 5, d4 = idx & 31;
  int i0 = sidx[2*n], i1 = sidx[2*n+1];
  float g0 = gwn[2*n], g1 = gwn[2*n+1];
  float4 a = ((const float4*)x1)[idx];
  float4 u = ((const float4*)eo)[(size_t)i0 * 32 + d4];
  float4 w = ((const float4*)eo)[(size_t)i1 * 32 + d4];
  float4 o = {a.x + g0*u.x + g1*w.x, a.y + g0*u.y + g1*w.y,
              a.z + g0*u.z + g1*w.z, a.w + g0*u.w + g1*w.w};
  ((float4*)out)[idx] = o;
  if (idx == 0) {
    float aux = 0.f;
    for (int e = 0; e < E; ++e)
      aux += ((float)ecnt[e] * (1.f / 16384.f)) * (psum[e] * (1.f / 8192.f));
    out[N * D] = 8.f * aux;
  }
}

extern "C" void kernel_launch(void* const* d_in, const int* in_sizes, int n_in,
                              void* d_out, int out_size, void* d_ws, size_t ws_size,
                              hipStream_t stream) {
  const float* x    = (const float*)d_in[0];
  const float* ln1g = (const float*)d_in[1];
  const float* ln1b = (const float*)d_in[2];
  const float* wq   = (const float*)d_in[3];
  const float* wk   = (const float*)d_in[4];
  const float* wv   = (const float*)d_in[5];
  const float* wp   = (const float*)d_in[6];
  const float* bp   = (const float*)d_in[7];
  const float* ln2g = (const float*)d_in[8];
  const float* ln2b = (const float*)d_in[9];
  const float* wg   = (const float*)d_in[10];
  const float* w1   = (const float*)d_in[11];
  const float* b1   = (const float*)d_in[12];
  const float* w2   = (const float*)d_in[13];
  const float* b2   = (const float*)d_in[14];
  float* out = (float*)d_out;
  float* ws = (float*)d_ws;
  const size_t M = 1u << 20;  // 1M floats
  float* Bq = ws + 1 * M;                         // x1 f32
  _Float16* qh  = (_Float16*)(ws + 2 * M);
  _Float16* xh  = (_Float16*)(ws + 2 * M);        // reuses qh region (qh dead post-attn)
  _Float16* kh  = (_Float16*)(ws + 2 * M + M / 2);
  _Float16* vTh = (_Float16*)(ws + 3 * M);
  float* part = ws + 3 * M + M / 2;               // 18*4*NQ = 4.5M floats
  float* eo   = part;                             // 8M floats; part dead after comb
  _Float16* w1pk = (_Float16*)(ws + 14 * M + M / 2);
  _Float16* w2pk = (_Float16*)(ws + 14 * M + 3 * (M / 4));
  size_t G0 = 15 * M;
  int*    ltok   = (int*)(ws + G0);                // 65536 ints
  int*    sidx   = (int*)(ws + G0 + 65536);        // 16384 ints
  float*  gwn    = ws + G0 + 81920;                // 16384 floats
  float*  psum   = ws + G0 + 98304;                // 8
  int*    ecnt   = (int*)(ws + G0 + 98312);        // 8
  int*    wcnt   = (int*)(ws + G0 + 98320);        // 4096 ints (512 blocks x 8)
  float*  wpsum  = ws + G0 + 102416;               // 4096 floats
  int4*   tokinfo= (int4*)(ws + G0 + 106512);      // 8192 int4 = 32768 fl
  float2* gws    = (float2*)(ws + G0 + 139280);    // 8192 float2 = 16384 fl
  _Float16* wqkvh = (_Float16*)(ws + G0 + 155664); // 49152 halves = 24576 fl
  _Float16* wqkvl = (_Float16*)(ws + G0 + 180240); // 24576 fl
  _Float16* wpph  = (_Float16*)(ws + G0 + 204816); // 8192 fl
  _Float16* wppl  = (_Float16*)(ws + G0 + 213008); // 8192 fl -> ends 221200

  pack_moe<<<dim3(32, 8, 2 * E), 64, 0, stream>>>(w1, w2, w1pk, w2pk);
  pack_attn<<<dim3(8, 8, 4), 64, 0, stream>>>(wq, wk, wv, wp, wqkvh, wqkvl, wpph, wppl);
  qkv_mfma<<<N / 16, 512, 0, stream>>>(x, ln1g, ln1b, wqkvh, wqkvl, qh, kh, vTh);
  attn_mfma<<<dim3(20, Bsz * H), 256, 0, stream>>>(qh, kh, vTh, part);
  comb_proj<<<N / 16, 512, 0, stream>>>(part, wpph, wppl, bp, x, ln2g, ln2b, wg,
                                        Bq, xh, wcnt, wpsum, tokinfo, gws);
  gate_scat<<<N / 64, 64, 0, stream>>>(wcnt, wpsum, tokinfo, gws, ltok, sidx, gwn, ecnt, psum);
  moe_mfma<<<dim3(N / 16, E), 256, 0, stream>>>(xh, w1pk, b1, w2pk, b2, ecnt, ltok, eo);
  finalize_kernel<<<(N * D / 4) / 256, 256, 0, stream>>>(Bq, eo, sidx, gwn, psum, ecnt, out);
}

// Round 15
// 112.249 us; speedup vs baseline: 1.0440x; 1.0440x over previous
//
#include <hip/hip_runtime.h>
#include <math.h>

#define Bsz 4
#define T 2048
#define D 128
#define H 8
#define HS 16
#define E 8
#define FF 512
#define N (Bsz*T)     // 8192
#define NQ (Bsz*H*T)  // 65536 query rows
#define EPS 1e-5f
#define SCALE2 0.36067376f   // 0.25 * log2(e)
#define SPLITS 8

typedef _Float16 h4 __attribute__((ext_vector_type(4)));
typedef _Float16 h2 __attribute__((ext_vector_type(2)));
typedef float f4 __attribute__((ext_vector_type(4)));
#define MFMA16 __builtin_amdgcn_mfma_f32_16x16x16f16
#define EXP2(x) __builtin_amdgcn_exp2f(x)

__device__ __forceinline__ float wave_sum(float v) {
#pragma unroll
  for (int off = 32; off >= 1; off >>= 1) v += __shfl_xor(v, off);
  return v;
}

// ---------------- merged MoE weight packing: z = e*2 + (0:w1, 1:w2) ----------------
__global__ void pack_moe(const float* __restrict__ w1, const float* __restrict__ w2,
                         _Float16* __restrict__ w1pk, _Float16* __restrict__ w2pk) {
  int ft = blockIdx.x, kd = blockIdx.y;
  int e = blockIdx.z >> 1, m = blockIdx.z & 1;
  int l = threadIdx.x, lg = l >> 4, lr = l & 15;
  h4 v;
  if (m == 0) {
    const float* src = w1 + (size_t)e * D * FF;
#pragma unroll
    for (int i = 0; i < 4; ++i)
      v[i] = (_Float16)src[(size_t)(16 * kd + 4 * lg + i) * FF + 16 * ft + lr];
    ((h4*)w1pk)[(((size_t)e * 32 + ft) * 8 + kd) * 64 + l] = v;
  } else {
    const float* src = w2 + (size_t)e * FF * D;
#pragma unroll
    for (int i = 0; i < 4; ++i)
      v[i] = (_Float16)src[(size_t)(16 * ft + 4 * lg + i) * D + 16 * kd + lr];
    ((h4*)w2pk)[(((size_t)e * 32 + ft) * 8 + kd) * 64 + l] = v;
  }
}

// ---------------- merged attn-side packing: z = 0..2 qkv (hi/lo), z=3 wp (hi/lo) --------
__global__ void pack_attn(const float* __restrict__ wq, const float* __restrict__ wk,
                          const float* __restrict__ wv, const float* __restrict__ wp,
                          _Float16* __restrict__ wqh, _Float16* __restrict__ wql,
                          _Float16* __restrict__ wph, _Float16* __restrict__ wpl) {
  int ot = blockIdx.x, kd = blockIdx.y, m = blockIdx.z;
  int l = threadIdx.x, lg = l >> 4, lr = l & 15;
  h4 vh, vl;
  if (m < 3) {
    const float* W = (m == 0 ? wq : (m == 1 ? wk : wv));
    float sc = (m == 0) ? SCALE2 : 1.f;
#pragma unroll
    for (int i = 0; i < 4; ++i) {
      float w = W[((size_t)ot * D + 16 * kd + 4 * lg + i) * HS + lr] * sc;
      _Float16 h = (_Float16)w;
      vh[i] = h;
      vl[i] = (_Float16)(w - (float)h);
    }
    size_t idx = (((size_t)m * 8 + ot) * 8 + kd) * 64 + l;
    ((h4*)wqh)[idx] = vh;
    ((h4*)wql)[idx] = vl;
  } else {
#pragma unroll
    for (int i = 0; i < 4; ++i) {
      float w = wp[(size_t)(16 * kd + 4 * lg + i) * D + 16 * ot + lr];
      _Float16 h = (_Float16)w;
      vh[i] = h;
      vl[i] = (_Float16)(w - (float)h);
    }
    size_t idx = ((size_t)ot * 8 + kd) * 64 + l;
    ((h4*)wph)[idx] = vh;
    ((h4*)wpl)[idx] = vl;
  }
}

// ---------------- fused LN1 + QKV split MFMA: 16 tokens, 8 waves (wave = head) ----------
__global__ __launch_bounds__(512) void qkv_mfma(
    const float* __restrict__ x, const float* __restrict__ g, const float* __restrict__ bln,
    const _Float16* __restrict__ wh, const _Float16* __restrict__ wl,
    _Float16* __restrict__ qh, _Float16* __restrict__ kh, _Float16* __restrict__ vTh) {
  __shared__ _Float16 xsh[16][136];
  __shared__ _Float16 xsl[16][136];
  int n0 = blockIdx.x * 16;
  int b = n0 >> 11, t0 = n0 & (T - 1);
  int tid = threadIdx.x;
  {  // LN for 16 rows: 32 threads/row, 4 elems/thread
    int i = tid >> 5, c = tid & 31;
    float4 v = *(const float4*)(x + (size_t)(n0 + i) * D + 4 * c);
    float s  = v.x + v.y + v.z + v.w;
    float s2 = v.x*v.x + v.y*v.y + v.z*v.z + v.w*v.w;
#pragma unroll
    for (int off = 16; off >= 1; off >>= 1) { s += __shfl_xor(s, off); s2 += __shfl_xor(s2, off); }
    float m = s * (1.f / D);
    float var = s2 * (1.f / D) - m * m;
    float r = rsqrtf(var + EPS);
    float4 gg = *(const float4*)(g + 4 * c);
    float4 bb = *(const float4*)(bln + 4 * c);
    float o0 = (v.x - m) * r * gg.x + bb.x;
    float o1 = (v.y - m) * r * gg.y + bb.y;
    float o2 = (v.z - m) * r * gg.z + bb.z;
    float o3 = (v.w - m) * r * gg.w + bb.w;
    _Float16 h0 = (_Float16)o0, h1 = (_Float16)o1, h2_ = (_Float16)o2, h3 = (_Float16)o3;
    *(h4*)&xsh[i][4 * c] = (h4){h0, h1, h2_, h3};
    *(h4*)&xsl[i][4 * c] = (h4){(_Float16)(o0 - (float)h0), (_Float16)(o1 - (float)h1),
                                (_Float16)(o2 - (float)h2_), (_Float16)(o3 - (float)h3)};
  }
  __syncthreads();
  int ot = tid >> 6;            // wave id = head 0..7
  int l = tid & 63, lg = l >> 4, lr = l & 15;
  h4 xfh[8], xfl[8];
#pragma unroll
  for (int kd = 0; kd < 8; ++kd) {
    xfh[kd] = *(const h4*)&xsh[lr][16 * kd + 4 * lg];
    xfl[kd] = *(const h4*)&xsl[lr][16 * kd + 4 * lg];
  }
  const h4* wbh = (const h4*)wh + l;
  const h4* wbl = (const h4*)wl + l;
  f4 aq = {0.f,0.f,0.f,0.f}, ak = aq, av = aq;
#pragma unroll
  for (int kd = 0; kd < 8; ++kd) {
    h4 wqh_ = wbh[((0 * 8 + ot) * 8 + kd) * 64];
    h4 wkh_ = wbh[((1 * 8 + ot) * 8 + kd) * 64];
    h4 wvh_ = wbh[((2 * 8 + ot) * 8 + kd) * 64];
    h4 wql_ = wbl[((0 * 8 + ot) * 8 + kd) * 64];
    h4 wkl_ = wbl[((1 * 8 + ot) * 8 + kd) * 64];
    h4 wvl_ = wbl[((2 * 8 + ot) * 8 + kd) * 64];
    aq = MFMA16(wqh_, xfh[kd], aq, 0, 0, 0);
    ak = MFMA16(wkh_, xfh[kd], ak, 0, 0, 0);
    av = MFMA16(xfh[kd], wvh_, av, 0, 0, 0);
    aq = MFMA16(wql_, xfh[kd], aq, 0, 0, 0);
    ak = MFMA16(wkl_, xfh[kd], ak, 0, 0, 0);
    av = MFMA16(xfl[kd], wvh_, av, 0, 0, 0);
    aq = MFMA16(wqh_, xfl[kd], aq, 0, 0, 0);
    ak = MFMA16(wkh_, xfl[kd], ak, 0, 0, 0);
    av = MFMA16(xfh[kd], wvl_, av, 0, 0, 0);
  }
  h4 q4 = {(_Float16)aq.x, (_Float16)aq.y, (_Float16)aq.z, (_Float16)aq.w};
  h4 k4 = {(_Float16)ak.x, (_Float16)ak.y, (_Float16)ak.z, (_Float16)ak.w};
  size_t qoff = ((size_t)(b * H + ot) * T + t0 + lr) * 16 + 4 * lg;
  *(h4*)(qh + qoff) = q4;
  *(h4*)(kh + qoff) = k4;
  h4 v4 = {(_Float16)av.x, (_Float16)av.y, (_Float16)av.z, (_Float16)av.w};
  *(h4*)(vTh + ((size_t)(b * H + ot) * 16 + lr) * T + t0 + 4 * lg) = v4;
}

// ---------------- MFMA flash attention partial: 4 active (qt,s) pairs per block ----------
__global__ __launch_bounds__(256) void attn_mfma(
    const _Float16* __restrict__ q, const _Float16* __restrict__ k,
    const _Float16* __restrict__ vT, float* __restrict__ part) {
  int bh = blockIdx.y;
  int p = blockIdx.x * 4 + (threadIdx.x >> 6);   // active pair index 0..143
  int c = 1;
  while (p >= 2 * c * (c - 1) + 4 * c) ++c;      // c in 1..8 (wave-uniform)
  int rem = p - 2 * c * (c - 1);
  int qt = (c - 1) * 4 + rem / c;
  int s = rem % c;
  int glo = 4 * s;
  int ghi = min(glo + 4, qt + 1);
  int l = threadIdx.x & 63;
  int lg = l >> 4, lr = l & 15;
  int q0 = qt * 64;
  const h4* qp = (const h4*)(q + ((size_t)bh * T + q0 + lr) * 16 + 4 * lg);
  h4 qf[4];
#pragma unroll
  for (int nt = 0; nt < 4; ++nt) qf[nt] = qp[nt * 64];
  f4 o0 = {0.f,0.f,0.f,0.f}, o1 = o0, o2 = o0, o3 = o0;
  float L0 = 0.f, L1 = 0.f, L2 = 0.f, L3 = 0.f;
  h4 kf[4], vf[4], kf2[4], vf2[4];
#define LOADKV(G, KK, VV) do { \
    int k0g = (G) * 64; \
    const h4* kp = (const h4*)(k + ((size_t)bh * T + k0g + lr) * 16 + 4 * lg); \
    _Pragma("unroll") for (int mt = 0; mt < 4; ++mt) KK[mt] = kp[mt * 64]; \
    const h4* vp = (const h4*)(vT + ((size_t)bh * 16 + lr) * T + k0g + 4 * lg); \
    _Pragma("unroll") for (int mt = 0; mt < 4; ++mt) VV[mt] = vp[mt * 4]; \
  } while (0)
  LOADKV(glo, kf, vf);
  for (int g = glo; g < ghi; ++g) {
    bool more = (g + 1 < ghi);
    if (more) LOADKV(g + 1, kf2, vf2);
    f4 z = {0.f,0.f,0.f,0.f};
    f4 sc[4][4];
#pragma unroll
    for (int mt = 0; mt < 4; ++mt)
#pragma unroll
      for (int nt = 0; nt < 4; ++nt)
        sc[mt][nt] = MFMA16(kf[mt], qf[nt], z, 0, 0, 0);
    if (g == qt) {  // diagonal tile: mask key > query
#pragma unroll
      for (int mt = 0; mt < 4; ++mt)
#pragma unroll
        for (int nt = 0; nt < 4; ++nt) {
          int kb = 16 * mt + 4 * lg, qb = 16 * nt + lr;
          if (kb + 0 > qb) sc[mt][nt].x = -1e30f;
          if (kb + 1 > qb) sc[mt][nt].y = -1e30f;
          if (kb + 2 > qb) sc[mt][nt].z = -1e30f;
          if (kb + 3 > qb) sc[mt][nt].w = -1e30f;
        }
    }
#define PROC(NT, L, O) do { \
    h4 pf[4]; \
    _Pragma("unroll") for (int mt = 0; mt < 4; ++mt) { \
      f4 a = sc[mt][NT]; h4 pv; float ex; \
      ex = EXP2(a.x); L += ex; pv.x = (_Float16)ex; \
      ex = EXP2(a.y); L += ex; pv.y = (_Float16)ex; \
      ex = EXP2(a.z); L += ex; pv.z = (_Float16)ex; \
      ex = EXP2(a.w); L += ex; pv.w = (_Float16)ex; \
      pf[mt] = pv; } \
    _Pragma("unroll") for (int mt = 0; mt < 4; ++mt) \
      O = MFMA16(vf[mt], pf[mt], O, 0, 0, 0); \
  } while (0)
    PROC(0, L0, o0);
    PROC(1, L1, o1);
    PROC(2, L2, o2);
    PROC(3, L3, o3);
#undef PROC
    if (more) {
#pragma unroll
      for (int mt = 0; mt < 4; ++mt) { kf[mt] = kf2[mt]; vf[mt] = vf2[mt]; }
    }
  }
#undef LOADKV
  L0 += __shfl_xor(L0, 16); L0 += __shfl_xor(L0, 32);
  L1 += __shfl_xor(L1, 16); L1 += __shfl_xor(L1, 32);
  L2 += __shfl_xor(L2, 16); L2 += __shfl_xor(L2, 32);
  L3 += __shfl_xor(L3, 16); L3 += __shfl_xor(L3, 32);
  float* pb = part + (size_t)s * 18 * NQ;
  int nbase = bh * T + q0 + lr;
#define WR(NT, L, O) do { int n = nbase + 16 * NT; \
    pb[(4 * lg + 0) * NQ + n] = O.x; pb[(4 * lg + 1) * NQ + n] = O.y; \
    pb[(4 * lg + 2) * NQ + n] = O.z; pb[(4 * lg + 3) * NQ + n] = O.w; \
    if (lg == 0) pb[16 * NQ + n] = L; \
  } while (0)
  WR(0, L0, o0);
  WR(1, L1, o1);
  WR(2, L2, o2);
  WR(3, L3, o3);
#undef WR
}

// ------- fused combine + proj + residual + LN2: 16 tokens, 512 threads -------
__global__ __launch_bounds__(512) void comb_proj(
    const float* __restrict__ part,
    const _Float16* __restrict__ wpph, const _Float16* __restrict__ wppl,
    const float* __restrict__ bp, const float* __restrict__ x,
    const float* __restrict__ ln2g, const float* __restrict__ ln2b,
    float* __restrict__ x1, float* __restrict__ xn2, _Float16* __restrict__ xh) {
  __shared__ float xP[16][132];
  int n0 = blockIdx.x * 16;
  int b = n0 >> 11, t0 = n0 & (T - 1);
  int tid = threadIdx.x;
  int ns = (t0 >> 8) + 1;   // uniform across block
  {  // phase 1: combine split partials -> xP[token][d]
    int i = tid & 15, h = (tid >> 4) & 7, r = tid >> 7;
    int n = (b * H + h) * T + t0 + i;
    float a0 = 0.f, a1 = 0.f, a2 = 0.f, a3 = 0.f, L = 0.f;
    for (int s = 0; s < ns; ++s) {
      const float* pb = part + (size_t)s * 18 * NQ;
      L  += pb[16 * NQ + n];
      a0 += pb[(4 * r + 0) * NQ + n];
      a1 += pb[(4 * r + 1) * NQ + n];
      a2 += pb[(4 * r + 2) * NQ + n];
      a3 += pb[(4 * r + 3) * NQ + n];
    }
    float inv = 1.f / L;
    float4 o = {a0 * inv, a1 * inv, a2 * inv, a3 * inv};
    *(float4*)&xP[i][h * 16 + 4 * r] = o;
  }
  __syncthreads();
  // phase 2: proj via split MFMA (wave ot = output tile)
  int ot = tid >> 6;
  int l = tid & 63, lg = l >> 4, lr = l & 15;
  h4 afh[8], afl[8];
#pragma unroll
  for (int kd = 0; kd < 8; ++kd) {
    float4 v = *(const float4*)&xP[lr][16 * kd + 4 * lg];
    _Float16 h0 = (_Float16)v.x, h1 = (_Float16)v.y, h2_ = (_Float16)v.z, h3 = (_Float16)v.w;
    afh[kd] = (h4){h0, h1, h2_, h3};
    afl[kd] = (h4){(_Float16)(v.x - (float)h0), (_Float16)(v.y - (float)h1),
                   (_Float16)(v.z - (float)h2_), (_Float16)(v.w - (float)h3)};
  }
  const h4* wbh = (const h4*)wpph + l;
  const h4* wbl = (const h4*)wppl + l;
  f4 acc = {0.f,0.f,0.f,0.f};
#pragma unroll
  for (int kd = 0; kd < 8; ++kd) {
    h4 wh_ = wbh[(ot * 8 + kd) * 64];
    h4 wl_ = wbl[(ot * 8 + kd) * 64];
    acc = MFMA16(wh_, afh[kd], acc, 0, 0, 0);
    acc = MFMA16(wl_, afh[kd], acc, 0, 0, 0);
    acc = MFMA16(wh_, afl[kd], acc, 0, 0, 0);
  }
  int o = 16 * ot + 4 * lg;
  float4 xr = *(const float4*)(x + (size_t)(n0 + lr) * D + o);
  float4 bb = *(const float4*)(bp + o);
  float4 ov = {acc.x + xr.x + bb.x, acc.y + xr.y + bb.y,
               acc.z + xr.z + bb.z, acc.w + xr.w + bb.w};
  *(float4*)(x1 + (size_t)(n0 + lr) * D + o) = ov;
  __syncthreads();            // all xP reads done
  *(float4*)&xP[lr][o] = ov;  // stage x1 rows for LN2
  __syncthreads();
  {  // phase 3: LN2 -> xn2 (f32, gate) + xh (f16, moe)
    int i = tid >> 5, c = tid & 31;
    float4 v = *(const float4*)&xP[i][4 * c];
    float s  = v.x + v.y + v.z + v.w;
    float s2 = v.x*v.x + v.y*v.y + v.z*v.z + v.w*v.w;
#pragma unroll
    for (int off = 16; off >= 1; off >>= 1) { s += __shfl_xor(s, off); s2 += __shfl_xor(s2, off); }
    float m = s * (1.f / D);
    float var = s2 * (1.f / D) - m * m;
    float r = rsqrtf(var + EPS);
    float4 gg = *(const float4*)(ln2g + 4 * c);
    float4 bv = *(const float4*)(ln2b + 4 * c);
    float4 on = {(v.x - m) * r * gg.x + bv.x, (v.y - m) * r * gg.y + bv.y,
                 (v.z - m) * r * gg.z + bv.z, (v.w - m) * r * gg.w + bv.w};
    *(float4*)(xn2 + (size_t)(n0 + i) * D + 4 * c) = on;
    h4 oh = {(_Float16)on.x, (_Float16)on.y, (_Float16)on.z, (_Float16)on.w};
    *(h4*)(xh + (size_t)(n0 + i) * D + 4 * c) = oh;
  }
}

// ---------------- gate phase 1: logits/softmax/top-2, wave histograms, ranks ----------------
__global__ void gate_part(const float* __restrict__ xn2, const float* __restrict__ wg,
                          int* __restrict__ wcnt, float* __restrict__ wpsum,
                          int4* __restrict__ tokinfo, float2* __restrict__ gws) {
  int lane = threadIdx.x;  // 64
  int blk = blockIdx.x;
  int n = blk * 64 + lane;
  const float4* xr = (const float4*)(xn2 + (size_t)n * D);
  float lg[E];
#pragma unroll
  for (int e = 0; e < E; ++e) lg[e] = 0.f;
  for (int dq = 0; dq < 32; ++dq) {
    float4 xv = xr[dq];
    int d = dq * 4;
#pragma unroll
    for (int e = 0; e < E; ++e)
      lg[e] += xv.x * wg[d*E + e] + xv.y * wg[(d+1)*E + e]
             + xv.z * wg[(d+2)*E + e] + xv.w * wg[(d+3)*E + e];
  }
  float mx = lg[0];
#pragma unroll
  for (int e = 1; e < E; ++e) mx = fmaxf(mx, lg[e]);
  float p[E]; float s = 0.f;
#pragma unroll
  for (int e = 0; e < E; ++e) { p[e] = __expf(lg[e] - mx); s += p[e]; }
  float invs = 1.f / s;
#pragma unroll
  for (int e = 0; e < E; ++e) p[e] *= invs;
#pragma unroll
  for (int e = 0; e < E; ++e) {
    float ve = wave_sum(p[e]);
    if (lane == 0) wpsum[blk * E + e] = ve;
  }
  int i1 = 0; float p1 = p[0];
#pragma unroll
  for (int e = 1; e < E; ++e) if (p[e] > p1) { p1 = p[e]; i1 = e; }
  int i2 = (i1 == 0) ? 1 : 0; float p2 = p[i2];
#pragma unroll
  for (int e = 0; e < E; ++e) if (e != i1 && p[e] > p2) { p2 = p[e]; i2 = e; }
  float gden = 1.f / (p1 + p2);
  unsigned long long lt = (1ULL << lane) - 1ULL;
  int woff0 = 0, woff1 = 0;
  int c0[E], ctot[E];
#pragma unroll
  for (int e = 0; e < E; ++e) {
    unsigned long long m0 = __ballot(i1 == e);
    c0[e] = __popcll(m0);
    if (i1 == e) woff0 = __popcll(m0 & lt);
  }
#pragma unroll
  for (int e = 0; e < E; ++e) {
    unsigned long long m1 = __ballot(i2 == e);
    if (i2 == e) woff1 = c0[e] + __popcll(m1 & lt);
    ctot[e] = c0[e] + __popcll(m1);
  }
  if (lane == 0) {
#pragma unroll
    for (int e = 0; e < E; ++e) wcnt[blk * E + e] = ctot[e];
  }
  tokinfo[n] = make_int4(i1, woff0, i2, woff1);
  gws[n] = make_float2(p1 * gden, p2 * gden);
}

// ---------------- gate phase 2: scan wave histograms -> bases, ecnt, psum ----------------
__global__ void gate_scan(const int* __restrict__ wcnt, const float* __restrict__ wpsum,
                          int* __restrict__ wbase, int* __restrict__ ecnt,
                          float* __restrict__ psum) {
  __shared__ int sc[128 * E];
  __shared__ float sp[128 * E];
  int tid = threadIdx.x;  // 64
  for (int i = tid; i < 128 * E; i += 64) { sc[i] = wcnt[i]; sp[i] = wpsum[i]; }
  __syncthreads();
  if (tid < E) {
    int run = 0;
    for (int b = 0; b < 128; ++b) { wbase[b * E + tid] = run; run += sc[b * E + tid]; }
    ecnt[tid] = run;
  } else if (tid >= 16 && tid < 16 + E) {
    int e = tid - 16;
    float sum = 0.f;
    for (int b = 0; b < 128; ++b) sum += sp[b * E + e];
    psum[e] = sum;
  }
}

// ---------------- gate phase 3: scatter tokens into expert buckets ----------------
__global__ void gate_scatter(const int4* __restrict__ tokinfo, const float2* __restrict__ gws,
                             const int* __restrict__ wbase,
                             int* __restrict__ ltok, int* __restrict__ sidx,
                             float* __restrict__ gwn) {
  int lane = threadIdx.x;  // 64
  int blk = blockIdx.x;
  int n = blk * 64 + lane;
  int4 ti = tokinfo[n];
  float2 g = gws[n];
  int pos0 = wbase[blk * E + ti.x] + ti.y;
  int pos1 = wbase[blk * E + ti.z] + ti.w;
  ltok[ti.x * N + pos0] = n;
  ltok[ti.z * N + pos1] = n;
  sidx[2 * n]     = ti.x * N + pos0;
  sidx[2 * n + 1] = ti.z * N + pos1;
  gwn[2 * n]     = g.x;
  gwn[2 * n + 1] = g.y;
}

// ---------------- MFMA grouped expert FFN: 16 tokens/block, 4-way FF split ----------------
__global__ __launch_bounds__(256) void moe_mfma(
    const _Float16* __restrict__ xh, const _Float16* __restrict__ w1pk,
    const float* __restrict__ b1, const _Float16* __restrict__ w2pk,
    const float* __restrict__ b2, const int* __restrict__ ecnt,
    const int* __restrict__ ltok, float* __restrict__ eo) {
  int e = blockIdx.y;
  int cnt = ecnt[e];
  int t0 = blockIdx.x * 16;
  if (t0 >= cnt) return;
  __shared__ int toks[16];
  __shared__ f4 red[3][8][64];
  int tid = threadIdx.x;
  if (tid < 16)
    toks[tid] = (t0 + tid < cnt) ? ltok[e * N + t0 + tid] : -1;
  __syncthreads();
  int fh = tid >> 6;            // wave = FF quarter 0..3
  int l = tid & 63;
  int lg = l >> 4, lr = l & 15;
  int tok = toks[lr];
  const h4* xp = (const h4*)(xh + (size_t)(tok < 0 ? 0 : tok) * D + 4 * lg);
  h4 xf[8];
#pragma unroll
  for (int kd = 0; kd < 8; ++kd) xf[kd] = xp[kd * 4];
  f4 oacc[8];
#pragma unroll
  for (int dt = 0; dt < 8; ++dt) oacc[dt] = (f4){0.f,0.f,0.f,0.f};
  const float* b1e = b1 + e * FF;
  const h4* w1b = (const h4*)w1pk + ((size_t)e * 32 + 8 * fh) * 8 * 64 + l;
  const h4* w2b = (const h4*)w2pk + ((size_t)e * 32 + 8 * fh) * 8 * 64 + l;
#pragma unroll 2
  for (int ftl = 0; ftl < 8; ++ftl) {
    f4 ha = {0.f,0.f,0.f,0.f};
#pragma unroll
    for (int kd = 0; kd < 8; ++kd)
      ha = MFMA16(w1b[(ftl * 8 + kd) * 64], xf[kd], ha, 0, 0, 0);
    int ft = 8 * fh + ftl;
    float4 bb = *(const float4*)&b1e[16 * ft + 4 * lg];
    h4 pf;
    {
      float z;
      z = ha.x + bb.x; pf.x = (_Float16)(0.5f * z * (1.f + erff(z * 0.70710678f)));
      z = ha.y + bb.y; pf.y = (_Float16)(0.5f * z * (1.f + erff(z * 0.70710678f)));
      z = ha.z + bb.z; pf.z = (_Float16)(0.5f * z * (1.f + erff(z * 0.70710678f)));
      z = ha.w + bb.w; pf.w = (_Float16)(0.5f * z * (1.f + erff(z * 0.70710678f)));
    }
#pragma unroll
    for (int dt = 0; dt < 8; ++dt)
      oacc[dt] = MFMA16(w2b[(ftl * 8 + dt) * 64], pf, oacc[dt], 0, 0, 0);
  }
  if (fh >= 1) {
#pragma unroll
    for (int dt = 0; dt < 8; ++dt) red[fh - 1][dt][l] = oacc[dt];
  }
  __syncthreads();
  if (fh == 0 && tok >= 0) {
    const float* b2e = b2 + e * D;
    float* eop = eo + ((size_t)(e * N + t0 + lr)) * 128;
#pragma unroll
    for (int dt = 0; dt < 8; ++dt) {
      f4 r0 = red[0][dt][l], r1 = red[1][dt][l], r2 = red[2][dt][l];
      float4 bb = *(const float4*)&b2e[16 * dt + 4 * lg];
      float4 o4 = {oacc[dt].x + r0.x + r1.x + r2.x + bb.x,
                   oacc[dt].y + r0.y + r1.y + r2.y + bb.y,
                   oacc[dt].z + r0.z + r1.z + r2.z + bb.z,
                   oacc[dt].w + r0.w + r1.w + r2.w + bb.w};
      *(float4*)(eop + 16 * dt + 4 * lg) = o4;
    }
  }
}

// ---------------- finalize: out = x1 + g0*eo[i0] + g1*eo[i1]; aux ----------------
__global__ void finalize_kernel(const float* __restrict__ x1, const float* __restrict__ eo,
                                const int* __restrict__ sidx, const float* __restrict__ gwn,
                                const float* __restrict__ psum, const int* __restrict__ ecnt,
                                float* __restrict__ out) {
  int idx = blockIdx.x * 256 + threadIdx.x;   // float4 index, N*D/4 total
  int n = idx >> 5, d4 = idx & 31;
  int i0 = sidx[2*n], i1 = sidx[2*n+1];
  float g0 = gwn[2*n], g1 = gwn[2*n+1];
  float4 a = ((const float4*)x1)[idx];
  float4 u = ((const float4*)eo)[(size_t)i0 * 32 + d4];
  float4 w = ((const float4*)eo)[(size_t)i1 * 32 + d4];
  float4 o = {a.x + g0*u.x + g1*w.x, a.y + g0*u.y + g1*w.y,
              a.z + g0*u.z + g1*w.z, a.w + g0*u.w + g1*w.w};
  ((float4*)out)[idx] = o;
  if (idx == 0) {
    float aux = 0.f;
    for (int e = 0; e < E; ++e)
      aux += ((float)ecnt[e] * (1.f / 16384.f)) * (psum[e] * (1.f / 8192.f));
    out[N * D] = 8.f * aux;
  }
}

extern "C" void kernel_launch(void* const* d_in, const int* in_sizes, int n_in,
                              void* d_out, int out_size, void* d_ws, size_t ws_size,
                              hipStream_t stream) {
  const float* x    = (const float*)d_in[0];
  const float* ln1g = (const float*)d_in[1];
  const float* ln1b = (const float*)d_in[2];
  const float* wq   = (const float*)d_in[3];
  const float* wk   = (const float*)d_in[4];
  const float* wv   = (const float*)d_in[5];
  const float* wp   = (const float*)d_in[6];
  const float* bp   = (const float*)d_in[7];
  const float* ln2g = (const float*)d_in[8];
  const float* ln2b = (const float*)d_in[9];
  const float* wg   = (const float*)d_in[10];
  const float* w1   = (const float*)d_in[11];
  const float* b1   = (const float*)d_in[12];
  const float* w2   = (const float*)d_in[13];
  const float* b2   = (const float*)d_in[14];
  float* out = (float*)d_out;
  float* ws = (float*)d_ws;
  const size_t M = 1u << 20;  // 1M floats
  float* Bq = ws + 1 * M;                         // x1 f32
  _Float16* qh  = (_Float16*)(ws + 2 * M);
  _Float16* xh  = (_Float16*)(ws + 2 * M);        // reuses qh region (qh dead post-attn)
  _Float16* kh  = (_Float16*)(ws + 2 * M + M / 2);
  _Float16* vTh = (_Float16*)(ws + 3 * M);
  float* part = ws + 3 * M + M / 2;
  float* eo   = part;
  float* xn2  = ws + 13 * M + M / 2;
  _Float16* w1pk = (_Float16*)(ws + 14 * M + M / 2);
  _Float16* w2pk = (_Float16*)(ws + 14 * M + 3 * (M / 4));
  size_t G0 = 15 * M;
  int*    ltok   = (int*)(ws + G0);                // 65536 ints
  int*    sidx   = (int*)(ws + G0 + 65536);        // 16384 ints
  float*  gwn    = ws + G0 + 81920;                // 16384 floats
  float*  psum   = ws + G0 + 98304;                // 8
  int*    ecnt   = (int*)(ws + G0 + 98312);        // 8
  int*    wcnt   = (int*)(ws + G0 + 98320);        // 1024 ints
  float*  wpsum  = ws + G0 + 99344;                // 1024 floats
  int*    wbase  = (int*)(ws + G0 + 100368);       // 1024 ints
  int4*   tokinfo= (int4*)(ws + G0 + 101392);      // 32768 floats-equiv
  float2* gws    = (float2*)(ws + G0 + 134160);    // 16384 floats-equiv
  _Float16* wqkvh = (_Float16*)(ws + G0 + 150544); // 24576 fl
  _Float16* wqkvl = (_Float16*)(ws + G0 + 175120); // 24576 fl
  _Float16* wpph  = (_Float16*)(ws + G0 + 199696); // 8192 fl
  _Float16* wppl  = (_Float16*)(ws + G0 + 207888); // 8192 fl

  pack_moe<<<dim3(32, 8, 2 * E), 64, 0, stream>>>(w1, w2, w1pk, w2pk);
  pack_attn<<<dim3(8, 8, 4), 64, 0, stream>>>(wq, wk, wv, wp, wqkvh, wqkvl, wpph, wppl);
  qkv_mfma<<<N / 16, 512, 0, stream>>>(x, ln1g, ln1b, wqkvh, wqkvl, qh, kh, vTh);
  attn_mfma<<<dim3(36, Bsz * H), 256, 0, stream>>>(qh, kh, vTh, part);
  comb_proj<<<N / 16, 512, 0, stream>>>(part, wpph, wppl, bp, x, ln2g, ln2b, Bq, xn2, xh);
  gate_part<<<N / 64, 64, 0, stream>>>(xn2, wg, wcnt, wpsum, tokinfo, gws);
  gate_scan<<<1, 64, 0, stream>>>(wcnt, wpsum, wbase, ecnt, psum);
  gate_scatter<<<N / 64, 64, 0, stream>>>(tokinfo, gws, wbase, ltok, sidx, gwn);
  moe_mfma<<<dim3(N / 16, E), 256, 0, stream>>>(xh, w1pk, b1, w2pk, b2, ecnt, ltok, eo);
  finalize_kernel<<<(N * D / 4) / 256, 256, 0, stream>>>(Bq, eo, sidx, gwn, psum, ecnt, out);
}